// Round 1
// baseline (442.929 us; speedup 1.0000x reference)
//
#include <hip/hip_runtime.h>

#define B_ 32
#define T_ 24
#define N_ 2048
#define D_ 64
#define K_ 32
#define H_ 16

__device__ __forceinline__ unsigned short f2bf(float f) {
    unsigned int u = __float_as_uint(f);
    return (unsigned short)((u + 0x7FFFu + ((u >> 16) & 1u)) >> 16);
}
__device__ __forceinline__ float bf2f(unsigned short h) {
    return __uint_as_float(((unsigned int)h) << 16);
}

// M[n][t][t2] = sum_h ad[h][t]*ad[h][t2],  ad[h][t] = sum_k ne[n][k]*adj[k][h][t]
__global__ void k_prepM(const float* __restrict__ ne, const float* __restrict__ adj,
                        float* __restrict__ M) {
    __shared__ float s_ne[K_];
    __shared__ float s_ad[H_ * T_];
    const int n = blockIdx.x;
    const int tid = threadIdx.x;  // 64 threads
    if (tid < K_) s_ne[tid] = ne[n * K_ + tid];
    __syncthreads();
    for (int f = tid; f < H_ * T_; f += 64) {
        const int h = f / T_, t = f % T_;
        float a = 0.f;
#pragma unroll
        for (int k = 0; k < K_; ++k) a += s_ne[k] * adj[(k * H_ + h) * T_ + t];
        s_ad[f] = a;
    }
    __syncthreads();
    for (int m = tid; m < T_ * T_; m += 64) {
        const int t = m / T_, t2 = m % T_;
        float a = 0.f;
#pragma unroll
        for (int h = 0; h < H_; ++h) a += s_ad[h * T_ + t] * s_ad[h * T_ + t2];
        M[n * (T_ * T_) + m] = a;
    }
}

// W[bt][i][o] = sum_k te[bt][k] * wp[k][i][o];  bias[bt][o] = sum_k te[bt][k]*bp[k][o]
__global__ void k_prepW(const float* __restrict__ te, const float* __restrict__ wp,
                        const float* __restrict__ bp, float* __restrict__ W,
                        float* __restrict__ bias) {
    const int bt = blockIdx.x;   // 0..B*T-1
    const int tid = threadIdx.x; // 256
    __shared__ float s_te[K_];
    if (tid < K_) s_te[tid] = te[bt * K_ + tid];
    __syncthreads();
    float4 acc[4] = {};
    for (int k = 0; k < K_; ++k) {
        const float tk = s_te[k];
        const float4* row = (const float4*)(wp + (size_t)k * (D_ * D_));
#pragma unroll
        for (int i = 0; i < 4; ++i) {
            float4 v = row[tid + i * 256];
            acc[i].x += tk * v.x; acc[i].y += tk * v.y;
            acc[i].z += tk * v.z; acc[i].w += tk * v.w;
        }
    }
    float4* Wout = (float4*)(W + (size_t)bt * (D_ * D_));
#pragma unroll
    for (int i = 0; i < 4; ++i) Wout[tid + i * 256] = acc[i];
    if (tid < D_) {
        float a = 0.f;
#pragma unroll
        for (int k = 0; k < K_; ++k) a += s_te[k] * bp[k * D_ + tid];
        bias[bt * D_ + tid] = a;
    }
}

// ret[b][t][n][d] (bf16) = sum_t' M[n][t][t'] * eb[b][t'][n][d]
__global__ void k_ret(const float* __restrict__ eb, const float* __restrict__ M,
                      unsigned short* __restrict__ ret) {
    const int b = blockIdx.y;
    const int nb = blockIdx.x * 64;
    const int tid = threadIdx.x; // 256
    const int d0 = (tid & 15) * 4;
    const int nl = tid >> 4; // 0..15
    for (int p = 0; p < 4; ++p) {
        const int n = nb + p * 16 + nl;
        float acc[T_][4];
#pragma unroll
        for (int t = 0; t < T_; ++t) {
            acc[t][0] = 0.f; acc[t][1] = 0.f; acc[t][2] = 0.f; acc[t][3] = 0.f;
        }
        const float* Mn = M + (size_t)n * (T_ * T_);
        for (int tp = 0; tp < T_; ++tp) {
            const float4 e = *(const float4*)(eb + (((size_t)(b * T_ + tp) * N_ + n) * D_ + d0));
            float4 mq[6];
#pragma unroll
            for (int q = 0; q < 6; ++q) mq[q] = *(const float4*)(Mn + tp * T_ + q * 4);
            float mr[T_];
#pragma unroll
            for (int q = 0; q < 6; ++q) {
                mr[q * 4 + 0] = mq[q].x; mr[q * 4 + 1] = mq[q].y;
                mr[q * 4 + 2] = mq[q].z; mr[q * 4 + 3] = mq[q].w;
            }
#pragma unroll
            for (int t = 0; t < T_; ++t) {
                const float mv = mr[t]; // = M[n][t][tp] by symmetry
                acc[t][0] += mv * e.x; acc[t][1] += mv * e.y;
                acc[t][2] += mv * e.z; acc[t][3] += mv * e.w;
            }
        }
#pragma unroll
        for (int t = 0; t < T_; ++t) {
            ushort4 u;
            u.x = f2bf(acc[t][0]); u.y = f2bf(acc[t][1]);
            u.z = f2bf(acc[t][2]); u.w = f2bf(acc[t][3]);
            *(ushort4*)(ret + (((size_t)(b * T_ + t) * N_ + n) * D_ + d0)) = u;
        }
    }
}

// out = leaky_relu(ret @ W[b,t] + bias[b,t] + eb)
#define SR_STRIDE 68
__global__ __launch_bounds__(256) void k_out(const unsigned short* __restrict__ ret,
                                             const float* __restrict__ W,
                                             const float* __restrict__ bias,
                                             const float* __restrict__ eb,
                                             float* __restrict__ out) {
    const int nb = blockIdx.x * 64;
    const int t = blockIdx.y;
    const int b = blockIdx.z;
    const int bt = b * T_ + t;
    const int tid = threadIdx.x; // 256
    __shared__ float sW[D_ * D_];             // [i][o]
    __shared__ unsigned short sR[D_ * SR_STRIDE]; // transposed [i][n]
    __shared__ float sB[D_];

    const float4* Wg = (const float4*)(W + (size_t)bt * (D_ * D_));
    float4* sW4 = (float4*)sW;
#pragma unroll
    for (int i = 0; i < 4; ++i) sW4[tid + i * 256] = Wg[tid + i * 256];
    if (tid < D_) sB[tid] = bias[bt * D_ + tid];

    const unsigned short* Rg = ret + ((size_t)bt * N_ + nb) * D_;
#pragma unroll
    for (int p = 0; p < 4; ++p) {
        const int f = tid * 4 + p * 1024;  // flat over [n][i]
        const int n = f >> 6, i0 = f & 63;
        const ushort4 u = *(const ushort4*)(Rg + (size_t)n * D_ + i0);
        sR[(i0 + 0) * SR_STRIDE + n] = u.x;
        sR[(i0 + 1) * SR_STRIDE + n] = u.y;
        sR[(i0 + 2) * SR_STRIDE + n] = u.z;
        sR[(i0 + 3) * SR_STRIDE + n] = u.w;
    }
    __syncthreads();

    const int o0 = (tid & 15) * 4;
    const int n0 = (tid >> 4) * 4;
    float acc[4][4] = {};
#pragma unroll
    for (int i = 0; i < D_; ++i) {
        const ushort4 rv = *(const ushort4*)(sR + i * SR_STRIDE + n0);
        const float r0 = bf2f(rv.x), r1 = bf2f(rv.y), r2 = bf2f(rv.z), r3 = bf2f(rv.w);
        const float4 w = *(const float4*)(sW + i * D_ + o0);
        acc[0][0] += r0 * w.x; acc[0][1] += r0 * w.y; acc[0][2] += r0 * w.z; acc[0][3] += r0 * w.w;
        acc[1][0] += r1 * w.x; acc[1][1] += r1 * w.y; acc[1][2] += r1 * w.z; acc[1][3] += r1 * w.w;
        acc[2][0] += r2 * w.x; acc[2][1] += r2 * w.y; acc[2][2] += r2 * w.z; acc[2][3] += r2 * w.w;
        acc[3][0] += r3 * w.x; acc[3][1] += r3 * w.y; acc[3][2] += r3 * w.z; acc[3][3] += r3 * w.w;
    }

    const float* ebg = eb + ((size_t)bt * N_ + nb) * D_;
    float* og = out + ((size_t)bt * N_ + nb) * D_;
    const float4 bv = *(const float4*)(sB + o0);
#pragma unroll
    for (int a = 0; a < 4; ++a) {
        const int n = n0 + a;
        const float4 e = *(const float4*)(ebg + (size_t)n * D_ + o0);
        float4 v;
        v.x = acc[a][0] + bv.x + e.x;
        v.y = acc[a][1] + bv.y + e.y;
        v.z = acc[a][2] + bv.z + e.z;
        v.w = acc[a][3] + bv.w + e.w;
        v.x = v.x >= 0.f ? v.x : 0.01f * v.x;
        v.y = v.y >= 0.f ? v.y : 0.01f * v.y;
        v.z = v.z >= 0.f ? v.z : 0.01f * v.z;
        v.w = v.w >= 0.f ? v.w : 0.01f * v.w;
        *(float4*)(og + (size_t)n * D_ + o0) = v;
    }
}

extern "C" void kernel_launch(void* const* d_in, const int* in_sizes, int n_in,
                              void* d_out, int out_size, void* d_ws, size_t ws_size,
                              hipStream_t stream) {
    const float* eb  = (const float*)d_in[0];
    const float* ne  = (const float*)d_in[1];
    const float* te  = (const float*)d_in[2];
    const float* adj = (const float*)d_in[3];
    const float* wp  = (const float*)d_in[4];
    const float* bp  = (const float*)d_in[5];
    float* out = (float*)d_out;

    char* ws = (char*)d_ws;
    const size_t ret_bytes  = (size_t)B_ * T_ * N_ * D_ * 2;        // 201,326,592
    const size_t M_bytes    = (size_t)N_ * T_ * T_ * 4;             //   4,718,592
    const size_t W_bytes    = (size_t)B_ * T_ * D_ * D_ * 4;        //  12,582,912
    unsigned short* ret = (unsigned short*)ws;
    float* M    = (float*)(ws + ret_bytes);
    float* W    = (float*)(ws + ret_bytes + M_bytes);
    float* bias = (float*)(ws + ret_bytes + M_bytes + W_bytes);

    k_prepM<<<N_, 64, 0, stream>>>(ne, adj, M);
    k_prepW<<<B_ * T_, 256, 0, stream>>>(te, wp, bp, W, bias);
    k_ret<<<dim3(N_ / 64, B_), 256, 0, stream>>>(eb, M, ret);
    k_out<<<dim3(N_ / 64, T_, B_), 256, 0, stream>>>(ret, W, bias, eb, out);
}

// Round 2
// 429.962 us; speedup vs baseline: 1.0302x; 1.0302x over previous
//
#include <hip/hip_runtime.h>

#define B_ 32
#define T_ 24
#define N_ 2048
#define D_ 64
#define K_ 32
#define H_ 16

typedef __attribute__((ext_vector_type(8))) short bf16x8;
typedef __attribute__((ext_vector_type(4))) float f32x4;

__device__ __forceinline__ unsigned short f2bf(float f) {
    unsigned int u = __float_as_uint(f);
    return (unsigned short)((u + 0x7FFFu + ((u >> 16) & 1u)) >> 16);
}
__device__ __forceinline__ float bf2f(unsigned short h) {
    return __uint_as_float(((unsigned int)h) << 16);
}

// M[n][t][t2] = sum_h ad[h][t]*ad[h][t2],  ad[h][t] = sum_k ne[n][k]*adj[k][h][t]
__global__ void k_prepM(const float* __restrict__ ne, const float* __restrict__ adj,
                        float* __restrict__ M) {
    __shared__ float s_ne[K_];
    __shared__ float s_ad[H_ * T_];
    const int n = blockIdx.x;
    const int tid = threadIdx.x;  // 64 threads
    if (tid < K_) s_ne[tid] = ne[n * K_ + tid];
    __syncthreads();
    for (int f = tid; f < H_ * T_; f += 64) {
        const int h = f / T_, t = f % T_;
        float a = 0.f;
#pragma unroll
        for (int k = 0; k < K_; ++k) a += s_ne[k] * adj[(k * H_ + h) * T_ + t];
        s_ad[f] = a;
    }
    __syncthreads();
    for (int m = tid; m < T_ * T_; m += 64) {
        const int t = m / T_, t2 = m % T_;
        float a = 0.f;
#pragma unroll
        for (int h = 0; h < H_; ++h) a += s_ad[h * T_ + t] * s_ad[h * T_ + t2];
        M[n * (T_ * T_) + m] = a;
    }
}

// Wt[bt][o][i] (bf16) = sum_k te[bt][k]*wp[k][i][o];  bias[bt][o] f32
__global__ __launch_bounds__(256) void k_prepW(const float* __restrict__ te,
                                               const float* __restrict__ wp,
                                               const float* __restrict__ bp,
                                               unsigned short* __restrict__ Wt,
                                               float* __restrict__ bias) {
    const int bt = blockIdx.x;   // 0..B*T-1
    const int tid = threadIdx.x; // 256
    __shared__ float s_te[K_];
    __shared__ float s_W[D_ * D_];  // [i][o] f32
    if (tid < K_) s_te[tid] = te[bt * K_ + tid];
    __syncthreads();
    float4 acc[4] = {};
    for (int k = 0; k < K_; ++k) {
        const float tk = s_te[k];
        const float4* row = (const float4*)(wp + (size_t)k * (D_ * D_));
#pragma unroll
        for (int i = 0; i < 4; ++i) {
            float4 v = row[tid + i * 256];
            acc[i].x += tk * v.x; acc[i].y += tk * v.y;
            acc[i].z += tk * v.z; acc[i].w += tk * v.w;
        }
    }
    float4* sW4 = (float4*)s_W;
#pragma unroll
    for (int i = 0; i < 4; ++i) sW4[tid + i * 256] = acc[i];
    if (tid < D_) {
        float a = 0.f;
#pragma unroll
        for (int k = 0; k < K_; ++k) a += s_te[k] * bp[k * D_ + tid];
        bias[bt * D_ + tid] = a;
    }
    __syncthreads();
    // transpose -> bf16: Wt[o][i]
    const int o = tid >> 2;
    const int i0 = (tid & 3) * 16;
    unsigned short* dst = Wt + (size_t)bt * (D_ * D_) + o * D_ + i0;
#pragma unroll
    for (int j = 0; j < 16; j += 4) {
        ushort4 u;
        u.x = f2bf(s_W[(i0 + j + 0) * D_ + o]);
        u.y = f2bf(s_W[(i0 + j + 1) * D_ + o]);
        u.z = f2bf(s_W[(i0 + j + 2) * D_ + o]);
        u.w = f2bf(s_W[(i0 + j + 3) * D_ + o]);
        *(ushort4*)(dst + j) = u;
    }
}

// ret[b][t][n][d] (bf16) = sum_t' M[n][t][t'] * eb[b][t'][n][d]
// block = (nb=16 nodes, b); eb slice staged in LDS bf16 (49KB); t tiled 3x8 -> no spills
__global__ __launch_bounds__(256) void k_ret(const float* __restrict__ eb,
                                             const float* __restrict__ M,
                                             unsigned short* __restrict__ ret) {
    const int b = blockIdx.y;
    const int nb = blockIdx.x * 16;
    const int tid = threadIdx.x; // 256
    __shared__ unsigned short s_eb[T_ * 16 * D_]; // [t][n][d], 49152 B

    // stage eb[b][0:24][nb:nb+16][0:64] -> bf16 LDS
#pragma unroll
    for (int it = 0; it < 24; ++it) {
        const int f4 = it * 256 + tid;      // float4 index
        const int e0 = f4 * 4;              // element index
        const int t = e0 >> 10;
        const int n = (e0 >> 6) & 15;
        const int d = e0 & 63;
        const float4 v = *(const float4*)(eb + ((size_t)(b * T_ + t) * N_ + nb + n) * D_ + d);
        ushort4 u;
        u.x = f2bf(v.x); u.y = f2bf(v.y); u.z = f2bf(v.z); u.w = f2bf(v.w);
        *(ushort4*)(s_eb + e0) = u;
    }
    __syncthreads();

    const int n = tid >> 4;        // 0..15
    const int dg = tid & 15;       // d = dg*4
    const float* Mn = M + (size_t)(nb + n) * (T_ * T_);

    for (int t0 = 0; t0 < T_; t0 += 8) {
        float acc[8][4] = {};
        for (int tp = 0; tp < T_; ++tp) {
            // M[n][t0+tt][tp] == M[n][tp][t0+tt] (symmetric) -> contiguous
            const float4 m0 = *(const float4*)(Mn + tp * T_ + t0);
            const float4 m1 = *(const float4*)(Mn + tp * T_ + t0 + 4);
            const ushort4 u = *(const ushort4*)(s_eb + tp * 1024 + n * 64 + dg * 4);
            const float e0 = bf2f(u.x), e1 = bf2f(u.y), e2 = bf2f(u.z), e3 = bf2f(u.w);
            const float mm[8] = {m0.x, m0.y, m0.z, m0.w, m1.x, m1.y, m1.z, m1.w};
#pragma unroll
            for (int tt = 0; tt < 8; ++tt) {
                acc[tt][0] += mm[tt] * e0;
                acc[tt][1] += mm[tt] * e1;
                acc[tt][2] += mm[tt] * e2;
                acc[tt][3] += mm[tt] * e3;
            }
        }
#pragma unroll
        for (int tt = 0; tt < 8; ++tt) {
            ushort4 u;
            u.x = f2bf(acc[tt][0]); u.y = f2bf(acc[tt][1]);
            u.z = f2bf(acc[tt][2]); u.w = f2bf(acc[tt][3]);
            *(ushort4*)(ret + ((size_t)(b * T_ + t0 + tt) * N_ + nb + n) * D_ + dg * 4) = u;
        }
    }
}

// out = leaky_relu(ret @ W[b,t] + bias[b,t] + eb)  -- MFMA 16x16x32 bf16, no LDS
__global__ __launch_bounds__(256) void k_out(const unsigned short* __restrict__ ret,
                                             const unsigned short* __restrict__ Wt,
                                             const float* __restrict__ bias,
                                             const float* __restrict__ eb,
                                             float* __restrict__ out) {
    const int t = blockIdx.y, b = blockIdx.z;
    const int bt = b * T_ + t;
    const int nb = blockIdx.x * 128;
    const int wave = threadIdx.x >> 6;
    const int lane = threadIdx.x & 63;
    const int lr = lane & 15;   // A row / B col / C col
    const int lh = lane >> 4;   // k-chunk / C row group
    const int n0 = nb + wave * 32;

    const unsigned short* Rb = ret + (size_t)bt * N_ * D_;
    const unsigned short* Wb = Wt + (size_t)bt * (D_ * D_);

    // B frags: B[k][o] from Wt[o][i]: lane holds Wt[o0+lr][kh*32 + lh*8 .. +7]
    bf16x8 Bf[4][2];
#pragma unroll
    for (int ot = 0; ot < 4; ++ot)
#pragma unroll
        for (int kh = 0; kh < 2; ++kh)
            Bf[ot][kh] = *(const bf16x8*)(Wb + (ot * 16 + lr) * D_ + kh * 32 + lh * 8);

    f32x4 acc[2][4] = {};
#pragma unroll
    for (int nt = 0; nt < 2; ++nt) {
        const unsigned short* Ar = Rb + (size_t)(n0 + nt * 16 + lr) * D_ + lh * 8;
        const bf16x8 Af0 = *(const bf16x8*)(Ar);
        const bf16x8 Af1 = *(const bf16x8*)(Ar + 32);
#pragma unroll
        for (int ot = 0; ot < 4; ++ot) {
            acc[nt][ot] = __builtin_amdgcn_mfma_f32_16x16x32_bf16(Af0, Bf[ot][0], acc[nt][ot], 0, 0, 0);
            acc[nt][ot] = __builtin_amdgcn_mfma_f32_16x16x32_bf16(Af1, Bf[ot][1], acc[nt][ot], 0, 0, 0);
        }
    }

    float bv[4];
#pragma unroll
    for (int ot = 0; ot < 4; ++ot) bv[ot] = bias[bt * D_ + ot * 16 + lr];

    const float* ebbt = eb + (size_t)bt * N_ * D_;
    float* obt = out + (size_t)bt * N_ * D_;
#pragma unroll
    for (int nt = 0; nt < 2; ++nt) {
#pragma unroll
        for (int r = 0; r < 4; ++r) {
            const int nn = n0 + nt * 16 + lh * 4 + r;
#pragma unroll
            for (int ot = 0; ot < 4; ++ot) {
                const int o = ot * 16 + lr;
                float v = acc[nt][ot][r] + bv[ot] + ebbt[(size_t)nn * D_ + o];
                v = v >= 0.f ? v : 0.01f * v;
                obt[(size_t)nn * D_ + o] = v;
            }
        }
    }
}

extern "C" void kernel_launch(void* const* d_in, const int* in_sizes, int n_in,
                              void* d_out, int out_size, void* d_ws, size_t ws_size,
                              hipStream_t stream) {
    const float* eb  = (const float*)d_in[0];
    const float* ne  = (const float*)d_in[1];
    const float* te  = (const float*)d_in[2];
    const float* adj = (const float*)d_in[3];
    const float* wp  = (const float*)d_in[4];
    const float* bp  = (const float*)d_in[5];
    float* out = (float*)d_out;

    char* ws = (char*)d_ws;
    const size_t ret_bytes = (size_t)B_ * T_ * N_ * D_ * 2;  // 201,326,592
    const size_t M_bytes   = (size_t)N_ * T_ * T_ * 4;       //   4,718,592
    const size_t Wt_bytes  = (size_t)B_ * T_ * D_ * D_ * 2;  //   6,291,456
    unsigned short* ret = (unsigned short*)ws;
    float* M            = (float*)(ws + ret_bytes);
    unsigned short* Wt  = (unsigned short*)(ws + ret_bytes + M_bytes);
    float* bias         = (float*)(ws + ret_bytes + M_bytes + Wt_bytes);

    k_prepM<<<N_, 64, 0, stream>>>(ne, adj, M);
    k_prepW<<<B_ * T_, 256, 0, stream>>>(te, wp, bp, Wt, bias);
    k_ret<<<dim3(N_ / 16, B_), 256, 0, stream>>>(eb, M, ret);
    k_out<<<dim3(N_ / 128, T_, B_), 256, 0, stream>>>(ret, Wt, bias, eb, out);
}

// Round 3
// 306.128 us; speedup vs baseline: 1.4469x; 1.4045x over previous
//
#include <hip/hip_runtime.h>

#define B_ 32
#define T_ 24
#define N_ 2048
#define D_ 64
#define K_ 32
#define H_ 16
#define NB 16

typedef __attribute__((ext_vector_type(8))) short bf16x8;
typedef __attribute__((ext_vector_type(4))) float f32x4;

__device__ __forceinline__ unsigned short f2bf(float f) {
    unsigned int u = __float_as_uint(f);
    return (unsigned short)((u + 0x7FFFu + ((u >> 16) & 1u)) >> 16);
}
__device__ __forceinline__ float bf2f(unsigned short h) {
    return __uint_as_float(((unsigned int)h) << 16);
}

// M[n][t][t2] = sum_h ad[h][t]*ad[h][t2],  ad[h][t] = sum_k ne[n][k]*adj[k][h][t]
__global__ void k_prepM(const float* __restrict__ ne, const float* __restrict__ adj,
                        float* __restrict__ M) {
    __shared__ float s_ne[K_];
    __shared__ float s_ad[H_ * T_];
    const int n = blockIdx.x;
    const int tid = threadIdx.x;  // 64 threads
    if (tid < K_) s_ne[tid] = ne[n * K_ + tid];
    __syncthreads();
    for (int f = tid; f < H_ * T_; f += 64) {
        const int h = f / T_, t = f % T_;
        float a = 0.f;
#pragma unroll
        for (int k = 0; k < K_; ++k) a += s_ne[k] * adj[(k * H_ + h) * T_ + t];
        s_ad[f] = a;
    }
    __syncthreads();
    for (int m = tid; m < T_ * T_; m += 64) {
        const int t = m / T_, t2 = m % T_;
        float a = 0.f;
#pragma unroll
        for (int h = 0; h < H_; ++h) a += s_ad[h * T_ + t] * s_ad[h * T_ + t2];
        M[n * (T_ * T_) + m] = a;
    }
}

// Wt[bt][o][i] (bf16) = sum_k te[bt][k]*wp[k][i][o];  bias[bt][o] f32
__global__ __launch_bounds__(256) void k_prepW(const float* __restrict__ te,
                                               const float* __restrict__ wp,
                                               const float* __restrict__ bp,
                                               unsigned short* __restrict__ Wt,
                                               float* __restrict__ bias) {
    const int bt = blockIdx.x;   // 0..B*T-1
    const int tid = threadIdx.x; // 256
    __shared__ float s_te[K_];
    __shared__ float s_W[D_ * D_];  // [i][o] f32
    if (tid < K_) s_te[tid] = te[bt * K_ + tid];
    __syncthreads();
    float4 acc[4] = {};
    for (int k = 0; k < K_; ++k) {
        const float tk = s_te[k];
        const float4* row = (const float4*)(wp + (size_t)k * (D_ * D_));
#pragma unroll
        for (int i = 0; i < 4; ++i) {
            float4 v = row[tid + i * 256];
            acc[i].x += tk * v.x; acc[i].y += tk * v.y;
            acc[i].z += tk * v.z; acc[i].w += tk * v.w;
        }
    }
    float4* sW4 = (float4*)s_W;
#pragma unroll
    for (int i = 0; i < 4; ++i) sW4[tid + i * 256] = acc[i];
    if (tid < D_) {
        float a = 0.f;
#pragma unroll
        for (int k = 0; k < K_; ++k) a += s_te[k] * bp[k * D_ + tid];
        bias[bt * D_ + tid] = a;
    }
    __syncthreads();
    // transpose -> bf16: Wt[o][i]
    const int o = tid >> 2;
    const int i0 = (tid & 3) * 16;
    unsigned short* dst = Wt + (size_t)bt * (D_ * D_) + o * D_ + i0;
#pragma unroll
    for (int j = 0; j < 16; j += 4) {
        ushort4 u;
        u.x = f2bf(s_W[(i0 + j + 0) * D_ + o]);
        u.y = f2bf(s_W[(i0 + j + 1) * D_ + o]);
        u.z = f2bf(s_W[(i0 + j + 2) * D_ + o]);
        u.w = f2bf(s_W[(i0 + j + 3) * D_ + o]);
        *(ushort4*)(dst + j) = u;
    }
}

// Fused: ret = M-mix of eb (registers, MFMA-A-frag layout) -> MFMA vs Wt -> epilogue.
// Block = (16-node tile, b). eb slice staged once in LDS (bf16, XOR-swizzled).
// Wave w handles t in [w*6, w*6+6), two passes of 3 t's.
__global__ __launch_bounds__(256, 3) void k_fused(const float* __restrict__ eb,
                                                  const float* __restrict__ M,
                                                  const unsigned short* __restrict__ Wt,
                                                  const float* __restrict__ bias,
                                                  float* __restrict__ out) {
    const int b = blockIdx.y;
    const int nb = blockIdx.x * NB;
    const int tid = threadIdx.x;
    const int wave = tid >> 6, lane = tid & 63;
    const int lr = lane & 15, lh = lane >> 4;

    __shared__ unsigned short s_eb[T_ * NB * D_]; // [t][n][d] bf16, row=128B, swizzled

    // ---- stage eb[b][:][nb:nb+16][:] -> LDS bf16 ----
    {
        const int n = tid >> 4;
        const int d0 = (tid & 15) * 4;
        const int inrow = (d0 * 2) ^ ((n & 7) << 4);
        char* dst0 = (char*)s_eb + n * 128 + inrow;
        const float* src = eb + ((size_t)(b * T_) * N_ + nb + n) * D_ + d0;
#pragma unroll 4
        for (int it = 0; it < T_; ++it) {
            const float4 v = *(const float4*)(src + (size_t)it * (N_ * D_));
            ushort4 u;
            u.x = f2bf(v.x); u.y = f2bf(v.y); u.z = f2bf(v.z); u.w = f2bf(v.w);
            *(ushort4*)(dst0 + it * (NB * 128)) = u;
        }
    }
    __syncthreads();

    const float* Mn = M + (size_t)(nb + lr) * (T_ * T_);
    const char* ebase = (const char*)s_eb;
    const int sw = (lr & 7) << 4;

    for (int pass = 0; pass < 2; ++pass) {
        const int tb = wave * 6 + pass * 3;
        float acc[3][16];
#pragma unroll
        for (int tt = 0; tt < 3; ++tt)
#pragma unroll
            for (int j = 0; j < 16; ++j) acc[tt][j] = 0.f;

#pragma unroll 4
        for (int tp = 0; tp < T_; ++tp) {
            const float* mrow = Mn + tp * T_ + tb;  // M[n][tp][tb..tb+2] == M[n][tb..][tp]
            const float m0 = mrow[0], m1 = mrow[1], m2 = mrow[2];
            const char* rowp = ebase + (tp * NB + lr) * 128;
            const bf16x8 e0 = *(const bf16x8*)(rowp + ((lh * 16) ^ sw));
            const bf16x8 e1 = *(const bf16x8*)(rowp + (((lh + 4) * 16) ^ sw));
            float ef[16];
#pragma unroll
            for (int j = 0; j < 8; ++j) {
                ef[j]     = bf2f((unsigned short)e0[j]);
                ef[8 + j] = bf2f((unsigned short)e1[j]);
            }
#pragma unroll
            for (int j = 0; j < 16; ++j) {
                acc[0][j] += m0 * ef[j];
                acc[1][j] += m1 * ef[j];
                acc[2][j] += m2 * ef[j];
            }
        }

        // convert to MFMA A-fragments: lane holds ret[t][n=lr][lh*8+j] and [32+lh*8+j]
        bf16x8 Af[3][2];
#pragma unroll
        for (int tt = 0; tt < 3; ++tt)
#pragma unroll
            for (int j = 0; j < 8; ++j) {
                Af[tt][0][j] = (short)f2bf(acc[tt][j]);
                Af[tt][1][j] = (short)f2bf(acc[tt][8 + j]);
            }

#pragma unroll
        for (int tt = 0; tt < 3; ++tt) {
            const int t = tb + tt;
            const int bt = b * T_ + t;
            const unsigned short* Wb = Wt + (size_t)bt * (D_ * D_);
            f32x4 C[4] = {};
#pragma unroll
            for (int ot = 0; ot < 4; ++ot) {
                const bf16x8 B0 = *(const bf16x8*)(Wb + (ot * 16 + lr) * D_ + lh * 8);
                const bf16x8 B1 = *(const bf16x8*)(Wb + (ot * 16 + lr) * D_ + 32 + lh * 8);
                C[ot] = __builtin_amdgcn_mfma_f32_16x16x32_bf16(Af[tt][0], B0, C[ot], 0, 0, 0);
                C[ot] = __builtin_amdgcn_mfma_f32_16x16x32_bf16(Af[tt][1], B1, C[ot], 0, 0, 0);
            }
            float bv[4];
#pragma unroll
            for (int ot = 0; ot < 4; ++ot) bv[ot] = bias[bt * D_ + ot * 16 + lr];

            float* obt = out + ((size_t)bt * N_ + nb) * D_;
#pragma unroll
            for (int r = 0; r < 4; ++r) {
                const int nn = lh * 4 + r;  // node within tile (C-row)
                const char* erow = ebase + (t * NB + nn) * 128;
                const int swn = (nn & 7) << 4;
#pragma unroll
                for (int ot = 0; ot < 4; ++ot) {
                    const int o = ot * 16 + lr;  // C-col
                    const unsigned short eu =
                        *(const unsigned short*)(erow + ((o * 2) ^ swn));
                    float v = C[ot][r] + bv[ot] + bf2f(eu);
                    v = v >= 0.f ? v : 0.01f * v;
                    obt[(size_t)nn * D_ + o] = v;
                }
            }
        }
    }
}

extern "C" void kernel_launch(void* const* d_in, const int* in_sizes, int n_in,
                              void* d_out, int out_size, void* d_ws, size_t ws_size,
                              hipStream_t stream) {
    const float* eb  = (const float*)d_in[0];
    const float* ne  = (const float*)d_in[1];
    const float* te  = (const float*)d_in[2];
    const float* adj = (const float*)d_in[3];
    const float* wp  = (const float*)d_in[4];
    const float* bp  = (const float*)d_in[5];
    float* out = (float*)d_out;

    char* ws = (char*)d_ws;
    const size_t M_bytes  = (size_t)N_ * T_ * T_ * 4;       // 4,718,592
    const size_t Wt_bytes = (size_t)B_ * T_ * D_ * D_ * 2;  // 6,291,456
    float* M           = (float*)ws;
    unsigned short* Wt = (unsigned short*)(ws + M_bytes);
    float* bias        = (float*)(ws + M_bytes + Wt_bytes);

    k_prepM<<<N_, 64, 0, stream>>>(ne, adj, M);
    k_prepW<<<B_ * T_, 256, 0, stream>>>(te, wp, bp, Wt, bias);
    k_fused<<<dim3(N_ / NB, B_), 256, 0, stream>>>(eb, M, Wt, bias, out);
}